// Round 2
// baseline (598.130 us; speedup 1.0000x reference)
//
#include <hip/hip_runtime.h>
#include <stdint.h>
#include <stddef.h>

#define NB_HEAD 8
#define DHEAD   32
#define RATE    2
#define B_      4
#define S_      2046
#define N_      2048
#define M_      1024
#define D_      256

// bf16 helpers (raw uint16 view)
__device__ __forceinline__ void bf2x2(uint32_t u, float& lo, float& hi) {
    union { uint32_t i; float f; } a, b;
    a.i = u << 16;            // low bf16 -> float
    b.i = u & 0xffff0000u;    // high bf16 -> float
    lo = a.f; hi = b.f;
}
__device__ __forceinline__ uint16_t f2bf(float f) {
    union { float f; uint32_t i; } v; v.f = f;
    uint32_t u = v.i;
    u += 0x7fffu + ((u >> 16) & 1u);   // round-nearest-even
    return (uint16_t)(u >> 16);
}

// ---------------------------------------------------------------------------
// Kernel 1: qkv = pad(x) @ W + b  (fp32 in, bf16 out to workspace)
//   layout qkv[p][i][d],  p = ((b*8 + h)*2 + r),  row n = i*2 + r, col = h*32+d
//   rows n >= 2046 are the zero-padded rows -> qkv row = bias
// grid: 8192 blocks (b*2048+n), block: 128 threads (2 output cols each)
// ---------------------------------------------------------------------------
__global__ __launch_bounds__(128) void proj_kernel(
    const float* __restrict__ x, const float* __restrict__ W,
    const float* __restrict__ bias, uint16_t* __restrict__ qkv)
{
    __shared__ float xs[D_];
    const int row = blockIdx.x;          // b*2048 + n
    const int b = row >> 11;
    const int n = row & 2047;
    const int tid = threadIdx.x;

    {   // stage x row in LDS; zero for padded rows
        int k = tid * 2;
        float v0 = 0.f, v1 = 0.f;
        if (n < S_) {
            float2 u = *(const float2*)(x + ((size_t)b * S_ + n) * D_ + k);
            v0 = u.x; v1 = u.y;
        }
        xs[k] = v0; xs[k + 1] = v1;
    }
    __syncthreads();

    const int c0 = tid * 2;
    float acc0 = bias[c0];
    float acc1 = bias[c0 + 1];
    #pragma unroll 8
    for (int k = 0; k < D_; ++k) {
        float2 w = *(const float2*)(W + (size_t)k * D_ + c0);
        float xv = xs[k];
        acc0 += xv * w.x;
        acc1 += xv * w.y;
    }

    const int i = n >> 1, r = n & 1;
    const int h = c0 >> 5, d = c0 & 31;        // c0 even -> d,d+1 contiguous
    size_t dst = ((((size_t)b * NB_HEAD + h) * RATE + r) * M_ + i) * DHEAD + d;
    uint32_t outw = (uint32_t)f2bf(acc0) | ((uint32_t)f2bf(acc1) << 16);
    *(uint32_t*)(qkv + dst) = outw;
}

// ---------------------------------------------------------------------------
// Kernel 2: flash-style attention, one wave per row (Q=K=V so scores are
// symmetric: row i's score set = {x_i . x_j} for all j, plus 3 local window
// entries {x_i . x_{i-1}, |x_i|^2, x_i . x_{i+1}} where out-of-range
// neighbors contribute score 0 with value 0 (zero padding).
//   64 problems x 1024 rows = 65536 waves; block = 4 waves (same problem).
// ---------------------------------------------------------------------------
__global__ __launch_bounds__(256) void attn_kernel(
    const uint16_t* __restrict__ qkv, float* __restrict__ out)
{
    const float SC = 0.17677669529663687f * 1.4426950408889634f; // 1/sqrt(32) * log2(e)
    const int tid  = threadIdx.x;
    const int wid  = tid >> 6;
    const int lane = tid & 63;
    const int gw = blockIdx.x * 4 + wid;     // 0..65535
    const int p  = gw >> 10;                 // problem
    const int i  = gw & 1023;                // row
    const uint16_t* Xp = qkv + (size_t)p * M_ * DHEAD;

    // load q = Xp[i] (wave-uniform; one cache line)
    float q[32];
    {
        const uint4* qp = (const uint4*)(Xp + (size_t)i * DHEAD);
        #pragma unroll
        for (int t = 0; t < 4; ++t) {
            uint4 u = qp[t];
            bf2x2(u.x, q[8*t+0], q[8*t+1]);
            bf2x2(u.y, q[8*t+2], q[8*t+3]);
            bf2x2(u.z, q[8*t+4], q[8*t+5]);
            bf2x2(u.w, q[8*t+6], q[8*t+7]);
        }
    }

    float Mx = -1e30f, L = 0.f;
    float O[32];
    #pragma unroll
    for (int d = 0; d < 32; ++d) O[d] = 0.f;

    for (int jb = 0; jb < M_; jb += 64) {
        const int j = jb + lane;
        const uint4* kp = (const uint4*)(Xp + (size_t)j * DHEAD);
        float xv[32];
        #pragma unroll
        for (int t = 0; t < 4; ++t) {
            uint4 u = kp[t];
            bf2x2(u.x, xv[8*t+0], xv[8*t+1]);
            bf2x2(u.y, xv[8*t+2], xv[8*t+3]);
            bf2x2(u.z, xv[8*t+4], xv[8*t+5]);
            bf2x2(u.w, xv[8*t+6], xv[8*t+7]);
        }
        float s0=0.f, s1=0.f, s2=0.f, s3=0.f;
        #pragma unroll
        for (int d = 0; d < 32; d += 4) {
            s0 += q[d]   * xv[d];
            s1 += q[d+1] * xv[d+1];
            s2 += q[d+2] * xv[d+2];
            s3 += q[d+3] * xv[d+3];
        }
        float s = ((s0 + s1) + (s2 + s3)) * SC;

        if (s > Mx) {                       // rare after warm-up
            float f = exp2f(Mx - s);
            L *= f;
            #pragma unroll
            for (int d = 0; d < 32; ++d) O[d] *= f;
            Mx = s;
        }
        float e = exp2f(s - Mx);
        L += e;
        #pragma unroll
        for (int d = 0; d < 32; ++d) O[d] += e * xv[d];
    }

    // ---- merge 64 lanes ----
    float Mw = Mx;
    #pragma unroll
    for (int off = 32; off >= 1; off >>= 1)
        Mw = fmaxf(Mw, __shfl_xor(Mw, off, 64));
    {
        float f = exp2f(Mx - Mw);
        L *= f;
        #pragma unroll
        for (int d = 0; d < 32; ++d) O[d] *= f;
    }
    #pragma unroll
    for (int off = 32; off >= 1; off >>= 1)
        L += __shfl_xor(L, off, 64);
    #pragma unroll
    for (int d = 0; d < 32; ++d) {
        #pragma unroll
        for (int off = 32; off >= 1; off >>= 1)
            O[d] += __shfl_xor(O[d], off, 64);
    }

    // ---- 3 local extras: j = i-1, i, i+1; OOB -> score 0 AND value 0 ----
    float Mr = Mw, Lr = L;
    #pragma unroll
    for (int t = 0; t < 3; ++t) {
        const int jn = i + t - 1;
        const bool valid = (jn >= 0) && (jn < M_);
        float xv[32];
        if (t == 1) {
            #pragma unroll
            for (int d = 0; d < 32; ++d) xv[d] = q[d];
        } else if (valid) {
            const uint4* kp = (const uint4*)(Xp + (size_t)jn * DHEAD);
            #pragma unroll
            for (int tt = 0; tt < 4; ++tt) {
                uint4 u = kp[tt];
                bf2x2(u.x, xv[8*tt+0], xv[8*tt+1]);
                bf2x2(u.y, xv[8*tt+2], xv[8*tt+3]);
                bf2x2(u.z, xv[8*tt+4], xv[8*tt+5]);
                bf2x2(u.w, xv[8*tt+6], xv[8*tt+7]);
            }
        } else {
            #pragma unroll
            for (int d = 0; d < 32; ++d) xv[d] = 0.f;
        }
        float s0=0.f, s1=0.f;
        #pragma unroll
        for (int d = 0; d < 32; d += 2) { s0 += q[d]*xv[d]; s1 += q[d+1]*xv[d+1]; }
        float s = (s0 + s1) * SC;           // == 0 exactly when OOB (xv==0)
        float nM = fmaxf(Mr, s);
        float fo = exp2f(Mr - nM);
        float e  = exp2f(s - nM);
        Lr = Lr * fo + e;
        #pragma unroll
        for (int d = 0; d < 32; ++d) O[d] = O[d] * fo + e * xv[d];
        Mr = nM;
    }

    // ---- write row (skip padded rows n >= 2046), fp32 output ----
    const int r_ = p & 1;
    const int h  = (p >> 1) & 7;
    const int b  = p >> 4;
    const int n  = i * 2 + r_;
    if (n < S_) {
        const float inv = 1.0f / Lr;
        float v0 = 0.f, v1 = 0.f;
        const int d0 = lane * 2;
        #pragma unroll
        for (int d = 0; d < 32; ++d) {
            if (d == d0)     v0 = O[d];
            if (d == d0 + 1) v1 = O[d];
        }
        if (lane < 16) {
            float2 u; u.x = v0 * inv; u.y = v1 * inv;
            size_t dst = ((size_t)b * S_ + n) * D_ + h * DHEAD + d0;
            *(float2*)(out + dst) = u;
        }
    }
}

extern "C" void kernel_launch(void* const* d_in, const int* in_sizes, int n_in,
                              void* d_out, int out_size, void* d_ws, size_t ws_size,
                              hipStream_t stream) {
    const float* x    = (const float*)d_in[0];   // (4, 2046, 256) fp32
    const float* W    = (const float*)d_in[1];   // (256, 256) fp32
    const float* bias = (const float*)d_in[2];   // (256,) fp32
    uint16_t* qkv = (uint16_t*)d_ws;             // [64][1024][32] bf16 = 4 MB
    float* out = (float*)d_out;                  // (4, 2046, 256) fp32

    hipLaunchKernelGGL(proj_kernel, dim3(B_ * N_ * D_ / 256), dim3(128), 0, stream,
                       x, W, bias, qkv);
    hipLaunchKernelGGL(attn_kernel, dim3(64 * M_ / 4), dim3(256), 0, stream,
                       qkv, out);
}

// Round 3
// 141.640 us; speedup vs baseline: 4.2229x; 4.2229x over previous
//
#include <hip/hip_runtime.h>
#include <stdint.h>
#include <stddef.h>

#define NB_HEAD 8
#define DHEAD   32
#define RATE    2
#define B_      4
#define S_      2046
#define N_      2048
#define M_      1024
#define D_      256

#define XT_S    1032                 // Xt row stride (elements), 1024+8 pad
#define P_S     72                   // P' row stride (elements), 64+8 pad
#define LDS_ELS (32*XT_S + 4*16*P_S) // 33024 + 4608 = 37632 els = 75264 B

typedef __attribute__((ext_vector_type(8))) short short8;
typedef __attribute__((ext_vector_type(4))) float f32x4;

__device__ __forceinline__ float bf2f(uint16_t u) {
    union { uint32_t i; float f; } v; v.i = ((uint32_t)u) << 16; return v.f;
}
__device__ __forceinline__ uint16_t f2bf(float f) {
    union { float f; uint32_t i; } v; v.f = f;
    uint32_t u = v.i;
    u += 0x7fffu + ((u >> 16) & 1u);   // RNE
    return (uint16_t)(u >> 16);
}
__device__ __forceinline__ short8 ld_frag(const uint16_t* p) {
    union { uint4 u; short8 s; } v;
    v.u = *(const uint4*)p;
    return v.s;
}

// ---------------------------------------------------------------------------
// Kernel 1: qkv = pad(x) @ W + b  (fp32 in, bf16 out, phase-separated layout)
//   qkv[p][i][d], p = ((b*8+h)*2+r), row n = i*2+r, col = h*32+d
//   8 rows per block: W L2 traffic 2.1 GB -> 262 MB vs round 2.
// ---------------------------------------------------------------------------
__global__ __launch_bounds__(256) void proj_kernel(
    const float* __restrict__ x, const float* __restrict__ W,
    const float* __restrict__ bias, uint16_t* __restrict__ qkv)
{
    __shared__ float xs[8][256];
    const int tid = threadIdx.x;
    const int g0  = blockIdx.x * 8;       // 8 rows, never straddles batch (2048%8==0)
    const int b   = g0 >> 11;
    const int n0  = g0 & 2047;
    {
        const int rr = tid >> 5;
        const int k0 = (tid & 31) * 8;
        const int n  = n0 + rr;
        float4 a = {0,0,0,0}, c4 = {0,0,0,0};
        if (n < S_) {
            const float* src = x + ((size_t)b * S_ + n) * D_ + k0;
            a  = *(const float4*)src;
            c4 = *(const float4*)(src + 4);
        }
        *(float4*)&xs[rr][k0]     = a;
        *(float4*)&xs[rr][k0 + 4] = c4;
    }
    __syncthreads();

    const int c = tid;
    float acc[8];
    const float bv = bias[c];
    #pragma unroll
    for (int rr = 0; rr < 8; ++rr) acc[rr] = bv;

    const float* Wc = W + c;
    #pragma unroll 4
    for (int k = 0; k < 256; ++k) {
        float wv = Wc[(size_t)k * D_];
        #pragma unroll
        for (int rr = 0; rr < 8; ++rr) acc[rr] = fmaf(xs[rr][k], wv, acc[rr]);
    }

    const int h = c >> 5, d = c & 31;
    #pragma unroll
    for (int rr = 0; rr < 8; ++rr) {
        const int n = n0 + rr;
        const int i = n >> 1, r = n & 1;
        size_t dst = ((((size_t)b * NB_HEAD + h) * RATE + r) * M_ + i) * DHEAD + d;
        qkv[dst] = f2bf(acc[rr]);
    }
}

// ---------------------------------------------------------------------------
// Kernel 2: MFMA flash attention.
//   512 blocks = 64 problems x 8 row-chunks(128). 4 waves, 32 rows/wave.
//   mfma_f32_16x16x32_bf16: A[m=lane&15][k=quad*8+j], B[n=lane&15][k=quad*8+j],
//   C/D: col=lane&15, row=quad*4+reg (guide-verified m89/m91/m120).
//   Contraction-dim permutation trick: P' col' = n*4+g  <->  Xt j' = (jj&15)*4|(jj>>4)
//   (same perm on both PV operands => legal), so P pack is one b64/reg.
// ---------------------------------------------------------------------------
__global__ __launch_bounds__(256, 2) void attn_kernel(
    const uint16_t* __restrict__ qkv, float* __restrict__ out)
{
    const float SCL = 0.17677669529663687f * 1.4426950408889634f; // 1/sqrt(32)*log2(e)
    extern __shared__ uint16_t smem[];
    const int tid  = threadIdx.x;
    const int w    = tid >> 6;
    const int lane = tid & 63;
    const int q    = lane >> 4;
    const int n16  = lane & 15;
    const int p    = blockIdx.x >> 3;
    const int chunk= blockIdx.x & 7;
    const uint16_t* Xp = qkv + (size_t)p * (M_ * DHEAD);

    uint16_t* sXt = smem;                         // [32][XT_S]
    uint16_t* sP  = smem + 32 * XT_S + w * (16 * P_S); // wave-private [16][P_S]

    // ---- stage Xt[d][s*64 + perm(jj)] = X[s*64+jj][d], once per block ----
    {
        const int o  = tid & 3;                   // d-octet
        const int jj = tid >> 2;                  // 0..63 tile-local row
        const int jp = ((jj & 15) << 2) | (jj >> 4);
        for (int s = 0; s < 16; ++s) {
            union { uint4 u; uint16_t h[8]; } v;
            v.u = *(const uint4*)(Xp + ((size_t)s * 64 + jj) * DHEAD + o * 8);
            #pragma unroll
            for (int dd = 0; dd < 8; ++dd)
                sXt[(o * 8 + dd) * XT_S + s * 64 + jp] = v.h[dd];
        }
    }
    __syncthreads();

    const int rbase = chunk * 128 + w * 32;
    const f32x4 kZ = {0.f, 0.f, 0.f, 0.f};

    // Q A-frags for the wave's two 16-row tiles
    short8 A0 = ld_frag(Xp + (size_t)(rbase + n16) * DHEAD + q * 8);
    short8 A1 = ld_frag(Xp + (size_t)(rbase + 16 + n16) * DHEAD + q * 8);

    f32x4 O[2][2];                 // [rt][h]
    float Mx[2][4], Lx[2][4];      // [rt][reg]
    #pragma unroll
    for (int rt = 0; rt < 2; ++rt) {
        O[rt][0] = kZ; O[rt][1] = kZ;
        #pragma unroll
        for (int r = 0; r < 4; ++r) { Mx[rt][r] = -1e30f; Lx[rt][r] = 0.f; }
    }

    // softmax + PV for one 16-row tile
    auto do_rt = [&](f32x4* S, short8 XF00, short8 XF01, short8 XF10, short8 XF11,
                     float* Mr, float* Lr, f32x4* Or) {
        float mx[4], nM[4], al[4], rs[4];
        #pragma unroll
        for (int r = 0; r < 4; ++r)
            mx[r] = fmaxf(fmaxf(S[0][r], S[1][r]), fmaxf(S[2][r], S[3][r]));
        #pragma unroll
        for (int r = 0; r < 4; ++r) {
            #pragma unroll
            for (int m = 1; m < 16; m <<= 1)
                mx[r] = fmaxf(mx[r], __shfl_xor(mx[r], m, 64));
            nM[r] = fmaxf(Mr[r], mx[r] * SCL);
            al[r] = exp2f(Mr[r] - nM[r]);
            Mr[r] = nM[r];
            rs[r] = 0.f;
        }
        uint32_t eu[4][4];
        #pragma unroll
        for (int g = 0; g < 4; ++g)
            #pragma unroll
            for (int r = 0; r < 4; ++r) {
                float ef = exp2f(fmaf(S[g][r], SCL, -nM[r]));
                uint32_t t = __float_as_uint(ef) & 0xffff0000u; // trunc to bf16
                eu[g][r] = t;
                rs[r] += __uint_as_float(t);                    // L consistent with P
            }
        #pragma unroll
        for (int r = 0; r < 4; ++r) {
            #pragma unroll
            for (int m = 1; m < 16; m <<= 1)
                rs[r] += __shfl_xor(rs[r], m, 64);
            Lr[r] = Lr[r] * al[r] + rs[r];
        }
        // pack P' (col' = n16*4+g) and write one b64 per reg
        #pragma unroll
        for (int r = 0; r < 4; ++r) {
            uint2 pk;
            pk.x = (eu[0][r] >> 16) | eu[1][r];
            pk.y = (eu[2][r] >> 16) | eu[3][r];
            *(uint2*)(sP + (q * 4 + r) * P_S + n16 * 4) = pk;
        }
        // rescale O by alpha (per row = per reg)
        #pragma unroll
        for (int h = 0; h < 2; ++h)
            #pragma unroll
            for (int r = 0; r < 4; ++r) Or[h][r] *= al[r];
        // P A-frags back from LDS (wave-private; lgkmcnt ordering by compiler)
        short8 P0 = ld_frag(sP + n16 * P_S + q * 8);
        short8 P1 = ld_frag(sP + n16 * P_S + 32 + q * 8);
        Or[0] = __builtin_amdgcn_mfma_f32_16x16x32_bf16(P0, XF00, Or[0], 0, 0, 0);
        Or[0] = __builtin_amdgcn_mfma_f32_16x16x32_bf16(P1, XF01, Or[0], 0, 0, 0);
        Or[1] = __builtin_amdgcn_mfma_f32_16x16x32_bf16(P0, XF10, Or[1], 0, 0, 0);
        Or[1] = __builtin_amdgcn_mfma_f32_16x16x32_bf16(P1, XF11, Or[1], 0, 0, 0);
    };

    // prefetch score B-frags for tile 0
    short8 Bf[4];
    #pragma unroll
    for (int g = 0; g < 4; ++g)
        Bf[g] = ld_frag(Xp + (size_t)(g * 16 + n16) * DHEAD + q * 8);

    for (int tile = 0; tile < 16; ++tile) {
        const int jb = tile * 64;
        f32x4 S0[4], S1[4];
        #pragma unroll
        for (int g = 0; g < 4; ++g) {
            S0[g] = __builtin_amdgcn_mfma_f32_16x16x32_bf16(A0, Bf[g], kZ, 0, 0, 0);
            S1[g] = __builtin_amdgcn_mfma_f32_16x16x32_bf16(A1, Bf[g], kZ, 0, 0, 0);
        }
        // prefetch next tile's B-frags (overlaps softmax below)
        short8 Bn[4];
        if (tile < 15) {
            #pragma unroll
            for (int g = 0; g < 4; ++g)
                Bn[g] = ld_frag(Xp + (size_t)(jb + 64 + g * 16 + n16) * DHEAD + q * 8);
        }
        // Xt B-frags for PV (contraction dim is permuted consistently with P')
        short8 XF[2][2];
        #pragma unroll
        for (int h = 0; h < 2; ++h)
            #pragma unroll
            for (int kc = 0; kc < 2; ++kc)
                XF[h][kc] = ld_frag(sXt + (size_t)(h * 16 + n16) * XT_S + jb + kc * 32 + q * 8);

        do_rt(S0, XF[0][0], XF[0][1], XF[1][0], XF[1][1], Mx[0], Lx[0], O[0]);
        do_rt(S1, XF[0][0], XF[0][1], XF[1][0], XF[1][1], Mx[1], Lx[1], O[1]);

        #pragma unroll
        for (int g = 0; g < 4; ++g) Bf[g] = Bn[g];
    }

    // ---- epilogue: 3 local extras per row + normalize + store ----
    const int rpar = p & 1;
    const int hh   = (p >> 1) & 7;
    const int b    = p >> 4;

    #pragma unroll
    for (int rt = 0; rt < 2; ++rt) {
        const int ebase = rbase + rt * 16;
        const short8 Art = rt ? A1 : A0;
        // extra-score B-frags: cols = rows (ebase-1 .. ebase+30), clamped; OOB masked later
        const int cr0 = min(max(ebase - 1 + n16, 0), M_ - 1);
        const int cr1 = min(max(ebase + 15 + n16, 0), M_ - 1);
        short8 BE0 = ld_frag(Xp + (size_t)cr0 * DHEAD + q * 8);
        short8 BE1 = ld_frag(Xp + (size_t)cr1 * DHEAD + q * 8);
        f32x4 SE0 = __builtin_amdgcn_mfma_f32_16x16x32_bf16(Art, BE0, kZ, 0, 0, 0);
        f32x4 SE1 = __builtin_amdgcn_mfma_f32_16x16x32_bf16(Art, BE1, kZ, 0, 0, 0);

        #pragma unroll
        for (int r = 0; r < 4; ++r) {
            const int m = q * 4 + r;
            const int i = ebase + m;
            float s3[3], xv[3][2];
            #pragma unroll
            for (int dlt = 0; dlt < 3; ++dlt) {       // delta = dlt-1
                const int cE = m + dlt;               // B-frag col = m+delta+1
                const int ls = (q << 4) | (cE & 15);
                float v0 = __shfl(SE0[r], ls, 64);
                float v1 = __shfl(SE1[r], ls, 64);
                float sraw = (cE < 16) ? v0 : v1;
                const bool valid = (dlt == 0) ? (i > 0)
                                 : (dlt == 2) ? (i < M_ - 1) : true;
                s3[dlt] = valid ? sraw * SCL : 0.0f;  // OOB -> score exactly 0
                const int iv = min(max(i + dlt - 1, 0), M_ - 1);
                #pragma unroll
                for (int h = 0; h < 2; ++h) {
                    float xvv = bf2f(Xp[(size_t)iv * DHEAD + h * 16 + n16]);
                    xv[dlt][h] = valid ? xvv : 0.0f;  // OOB -> value 0
                }
            }
            float nM = fmaxf(fmaxf(Mx[rt][r], s3[0]), fmaxf(s3[1], s3[2]));
            float al = exp2f(Mx[rt][r] - nM);
            float e0 = exp2f(s3[0] - nM);
            float e1 = exp2f(s3[1] - nM);
            float e2 = exp2f(s3[2] - nM);
            float Lf = Lx[rt][r] * al + e0 + e1 + e2;
            float inv = 1.0f / Lf;
            if (i < M_ - 1) {                          // rows i=1023 are padding
                const size_t rowb = ((size_t)b * S_ + 2 * i + rpar) * D_ + hh * DHEAD;
                #pragma unroll
                for (int h = 0; h < 2; ++h) {
                    float val = (O[rt][h][r] * al + e0 * xv[0][h] + e1 * xv[1][h]
                                 + e2 * xv[2][h]) * inv;
                    out[rowb + h * 16 + n16] = val;
                }
            }
        }
    }
}

extern "C" void kernel_launch(void* const* d_in, const int* in_sizes, int n_in,
                              void* d_out, int out_size, void* d_ws, size_t ws_size,
                              hipStream_t stream) {
    const float* x    = (const float*)d_in[0];   // (4, 2046, 256) fp32
    const float* W    = (const float*)d_in[1];   // (256, 256) fp32
    const float* bias = (const float*)d_in[2];   // (256,) fp32
    uint16_t* qkv = (uint16_t*)d_ws;             // [64][1024][32] bf16 = 4 MB
    float* out = (float*)d_out;                  // (4, 2046, 256) fp32

    static const size_t lds_bytes = LDS_ELS * sizeof(uint16_t); // 75264 B
    hipFuncSetAttribute((const void*)attn_kernel,
                        hipFuncAttributeMaxDynamicSharedMemorySize,
                        (int)lds_bytes);

    hipLaunchKernelGGL(proj_kernel, dim3(B_ * N_ / 8), dim3(256), 0, stream,
                       x, W, bias, qkv);
    hipLaunchKernelGGL(attn_kernel, dim3(64 * 8), dim3(256), lds_bytes, stream,
                       qkv, out);
}